// Round 9
// baseline (352.728 us; speedup 1.0000x reference)
//
#include <hip/hip_runtime.h>
#include <stdint.h>

typedef unsigned short ushort_t;
typedef __attribute__((ext_vector_type(8))) unsigned short ushort8v;
typedef __attribute__((ext_vector_type(8))) short short8v;  // 8 bf16 = 4 VGPRs
typedef __attribute__((ext_vector_type(4))) float f32x4;    // MFMA C/D frag

__device__ __forceinline__ float bf2f(ushort_t u) {
  union { unsigned int i; float f; } v;
  v.i = ((unsigned int)u) << 16;
  return v.f;
}
__device__ __forceinline__ ushort_t f2bf(float f) {
  union { float f; unsigned int i; } v;
  v.f = f;
  unsigned int r = v.i + 0x7FFFu + ((v.i >> 16) & 1u);  // RNE
  return (ushort_t)(r >> 16);
}

// Load 8 elements as bf16 bit-pattern vector (cvt if source is fp32).
__device__ __forceinline__ ushort8v load8bf(const ushort_t* __restrict__ p) {
  return *(const ushort8v*)p;
}
__device__ __forceinline__ ushort8v load8bf(const float* __restrict__ p) {
  const float4 a = *(const float4*)p;
  const float4 b = *(const float4*)(p + 4);
  ushort8v r;
  r[0] = f2bf(a.x); r[1] = f2bf(a.y); r[2] = f2bf(a.z); r[3] = f2bf(a.w);
  r[4] = f2bf(b.x); r[5] = f2bf(b.y); r[6] = f2bf(b.z); r[7] = f2bf(b.w);
  return r;
}
__device__ __forceinline__ void storeC(float* p, float v) { *p = v; }
__device__ __forceinline__ void storeC(ushort_t* p, float v) { *p = f2bf(v); }

// pixel index (b,y,x layout, 56x56) -> element offset of that 256-chan row
// inside the patch-major packed tensor xpat[1024][12544].
// (7x7 stride-7 conv: im2col is a pure row permutation.)
__device__ __forceinline__ size_t pp_off(unsigned g) {
  const unsigned b = g / 3136u;
  const unsigned r = g - b * 3136u;
  const unsigned y = r / 56u, xx = r - y * 56u;
  const unsigned ty = y / 7u, dy = y - ty * 7u;
  const unsigned tx = xx / 7u, dx = xx - tx * 7u;
  return ((size_t)((b * 64u + ty * 8u + tx) * 49u + dy * 7u + dx)) << 8;
}

// ---------------------------------------------------------------------------
// Transpose + fp32->bf16: W[K][N] -> WT[N][K].  32x32 tiles, 256 threads.
// ---------------------------------------------------------------------------
__global__ __launch_bounds__(256) void transpose_cvt(
    const float* __restrict__ W, ushort_t* __restrict__ WT, int K, int N) {
  __shared__ float tile[32][33];
  const int t = threadIdx.x;
  const int k0 = blockIdx.y * 32;
  const int n0 = blockIdx.x * 32;
  {
    const int r = t >> 3, c4 = (t & 7) * 4;
    const float4 v = *(const float4*)(W + (size_t)(k0 + r) * N + n0 + c4);
    tile[r][c4] = v.x; tile[r][c4 + 1] = v.y;
    tile[r][c4 + 2] = v.z; tile[r][c4 + 3] = v.w;
  }
  __syncthreads();
  {
    const int rn = t >> 3, ck = (t & 7) * 4;
    union { ushort_t u[4]; uint2 v; } o;
#pragma unroll
    for (int j = 0; j < 4; ++j) o.u[j] = f2bf(tile[ck + j][rn]);
    *(uint2*)(WT + (size_t)(n0 + rn) * K + k0 + ck) = o.v;
  }
}

// ---------------------------------------------------------------------------
// fp32 -> bf16 bulk convert (n % 1024 == 0), 4 elems/thread.
// ---------------------------------------------------------------------------
__global__ __launch_bounds__(256) void cvt_f32_bf16(
    const float* __restrict__ in, ushort_t* __restrict__ out) {
  const int i = (blockIdx.x * 256 + threadIdx.x) * 4;
  const float4 v = *(const float4*)(in + i);
  union { ushort_t u[4]; uint2 q; } o;
  o.u[0] = f2bf(v.x); o.u[1] = f2bf(v.y);
  o.u[2] = f2bf(v.z); o.u[3] = f2bf(v.w);
  *(uint2*)(out + i) = o.q;
}

// ---------------------------------------------------------------------------
// x [50176][256] fp32 -> xpat [1024][12544] bf16, patch-major (im2col packed).
// 8 elems/thread; reads coalesced, writes in 512B row chunks.
// ---------------------------------------------------------------------------
__global__ __launch_bounds__(256) void cvt_im2col(
    const float* __restrict__ x, ushort_t* __restrict__ xp) {
  const int e = (blockIdx.x * 256 + threadIdx.x) * 8;
  const unsigned p = ((unsigned)e) >> 8;
  const int c = e & 255;
  const float4 a = *(const float4*)(x + e);
  const float4 b = *(const float4*)(x + e + 4);
  ushort8v o;
  o[0] = f2bf(a.x); o[1] = f2bf(a.y); o[2] = f2bf(a.z); o[3] = f2bf(a.w);
  o[4] = f2bf(b.x); o[5] = f2bf(b.y); o[6] = f2bf(b.z); o[7] = f2bf(b.w);
  *(ushort8v*)(xp + pp_off(p) + c) = o;
}

// ---------------------------------------------------------------------------
// Unified MFMA NT GEMM body, REG-STAGED pipeline, PREFETCH DISTANCE 2.
// r8 proven parts kept: r6 thread->global map (quad-contiguous reads, 2100
// GB/s) + LDS XOR swizzle (write conflicts 9.6M->3.2M).  r8 residual: all
// pipes idle (Mfma 12%, HBM 26%) -- loads issued top-of-step, consumed
// bottom-of-same-step: cover < 1 MFMA phase vs ~900cy miss latency.
// This round: TWO named register sets (static indexing, rule #20; loop
// unrolled x2 with compile-time parity), so a tile's loads get TWO full
// steps of cover.  Step t (parity p): ds_write tile t+1 (from set (t+1)&1)
// into buf[(t+1)&1] (other buffer, last read 2 barriers ago -- safe);
// issue loads tile t+3 into same set; MFMA from buf[t&1]; barrier.
// nst is even for all users (8/16/28).
// MODE: 0 = bf16 store, no bias; 1 = fp32 store + bias; 2 = fp32 atomicAdd.
// PERMA: A rows indexed through pp_off (loop-invariant, computed once).
// ---------------------------------------------------------------------------
template <int MODE, bool PERMA>
__device__ __forceinline__ void gemm_body(
    const ushort_t* __restrict__ A, const ushort_t* __restrict__ BT,
    const float* __restrict__ bias, void* __restrict__ Cv,
    int N, int K, int m0, int n0, int kbeg, int kend) {
  __shared__ ushort_t lA[2][4096];
  __shared__ ushort_t lB[2][4096];
  const int t = threadIdx.x;
  const int lane = t & 63;
  const int wv = t >> 6;
  const int wm = wv >> 1, wn = wv & 1;
  const int sm = t >> 2;   // row owner (r6 map: quad-contiguous global reads)
  const int kq = t & 3;    // 16B chunk within 32-wide K tile

  // LDS slot swizzle (r8 proven).  wslot/rdsw are loop-invariant.
  const int row16 = sm & 15;
  const int wslot = kq * 16 + (row16 ^ kq);
  const int rdsw = (lane ^ ((lane >> 4) & 3)) * 8;  // shorts

  const ushort_t* aR[2];
  const ushort_t* bR[2];
  int off[2];
#pragma unroll
  for (int h = 0; h < 2; ++h) {
    const int m = h * 64 + sm;  // 0..127
    off[h] = (h * 4 + wv) * 512 + wslot * 8;
    size_t aoff;
    if (PERMA)
      aoff = pp_off((unsigned)(m0 + m));
    else
      aoff = (size_t)(m0 + m) * K;
    aR[h] = A + aoff + kq * 8;
    bR[h] = BT + (size_t)(n0 + m) * K + kq * 8;
  }

  f32x4 acc[4][4] = {};
  const int nst = (kend - kbeg) >> 5;  // K-steps, even for all users

  // Two named staging sets (NO runtime indexing -- rule #20).
  // setA holds even-parity tiles (2,4,..), setB odd-parity (1,3,..).
  ushort8v avA0, avA1, bvA0, bvA1;
  ushort8v avB0, avB1, bvB0, bvB1;

  // prologue: tile 0 -> LDS buf0 directly; tile 1 -> setB; tile 2 -> setA
  {
    ushort8v a0 = *(const ushort8v*)(aR[0] + kbeg);
    ushort8v a1 = *(const ushort8v*)(aR[1] + kbeg);
    ushort8v b0 = *(const ushort8v*)(bR[0] + kbeg);
    ushort8v b1 = *(const ushort8v*)(bR[1] + kbeg);
    *(ushort8v*)&lA[0][off[0]] = a0;
    *(ushort8v*)&lA[0][off[1]] = a1;
    *(ushort8v*)&lB[0][off[0]] = b0;
    *(ushort8v*)&lB[0][off[1]] = b1;
  }
  if (1 < nst) {
    const int nk = kbeg + 32;
    avB0 = *(const ushort8v*)(aR[0] + nk);
    avB1 = *(const ushort8v*)(aR[1] + nk);
    bvB0 = *(const ushort8v*)(bR[0] + nk);
    bvB1 = *(const ushort8v*)(bR[1] + nk);
  }
  if (2 < nst) {
    const int nk = kbeg + 64;
    avA0 = *(const ushort8v*)(aR[0] + nk);
    avA1 = *(const ushort8v*)(aR[1] + nk);
    bvA0 = *(const ushort8v*)(bR[0] + nk);
    bvA1 = *(const ushort8v*)(bR[1] + nk);
  }
  __syncthreads();

  for (int st = 0; st < nst; st += 2) {
    // ---- even step st: MFMA buf0; write tile st+1 (setB) -> buf1;
    //      issue loads tile st+3 -> setB
    if (st + 1 < nst) {
      *(ushort8v*)&lA[1][off[0]] = avB0;
      *(ushort8v*)&lA[1][off[1]] = avB1;
      *(ushort8v*)&lB[1][off[0]] = bvB0;
      *(ushort8v*)&lB[1][off[1]] = bvB1;
    }
    if (st + 3 < nst) {
      const int nk = kbeg + (st + 3) * 32;
      avB0 = *(const ushort8v*)(aR[0] + nk);
      avB1 = *(const ushort8v*)(aR[1] + nk);
      bvB0 = *(const ushort8v*)(bR[0] + nk);
      bvB1 = *(const ushort8v*)(bR[1] + nk);
    }
    {
      short8v af[4], bfr[4];
#pragma unroll
      for (int i = 0; i < 4; ++i) {
        af[i] = *(const short8v*)&lA[0][(wm * 4 + i) * 512 + rdsw];
        bfr[i] = *(const short8v*)&lB[0][(wn * 4 + i) * 512 + rdsw];
      }
#pragma unroll
      for (int i = 0; i < 4; ++i)
#pragma unroll
        for (int j = 0; j < 4; ++j)
          acc[i][j] = __builtin_amdgcn_mfma_f32_16x16x32_bf16(
              af[i], bfr[j], acc[i][j], 0, 0, 0);
    }
    __syncthreads();
    if (st + 1 >= nst) break;

    // ---- odd step st+1: MFMA buf1; write tile st+2 (setA) -> buf0;
    //      issue loads tile st+4 -> setA
    if (st + 2 < nst) {
      *(ushort8v*)&lA[0][off[0]] = avA0;
      *(ushort8v*)&lA[0][off[1]] = avA1;
      *(ushort8v*)&lB[0][off[0]] = bvA0;
      *(ushort8v*)&lB[0][off[1]] = bvA1;
    }
    if (st + 4 < nst) {
      const int nk = kbeg + (st + 4) * 32;
      avA0 = *(const ushort8v*)(aR[0] + nk);
      avA1 = *(const ushort8v*)(aR[1] + nk);
      bvA0 = *(const ushort8v*)(bR[0] + nk);
      bvA1 = *(const ushort8v*)(bR[1] + nk);
    }
    {
      short8v af[4], bfr[4];
#pragma unroll
      for (int i = 0; i < 4; ++i) {
        af[i] = *(const short8v*)&lA[1][(wm * 4 + i) * 512 + rdsw];
        bfr[i] = *(const short8v*)&lB[1][(wn * 4 + i) * 512 + rdsw];
      }
#pragma unroll
      for (int i = 0; i < 4; ++i)
#pragma unroll
        for (int j = 0; j < 4; ++j)
          acc[i][j] = __builtin_amdgcn_mfma_f32_16x16x32_bf16(
              af[i], bfr[j], acc[i][j], 0, 0, 0);
    }
    __syncthreads();
  }

  const int col = lane & 15, rq = (lane >> 4) * 4;
#pragma unroll
  for (int i = 0; i < 4; ++i) {
    const int mb = m0 + (wm * 4 + i) * 16 + rq;
#pragma unroll
    for (int j = 0; j < 4; ++j) {
      const int nb = n0 + (wn * 4 + j) * 16 + col;
      if (MODE == 0) {
        ushort_t* C = (ushort_t*)Cv;
#pragma unroll
        for (int r = 0; r < 4; ++r)
          C[(size_t)(mb + r) * N + nb] = f2bf(acc[i][j][r]);
      } else if (MODE == 1) {
        float* C = (float*)Cv;
        const float badd = bias[nb];
#pragma unroll
        for (int r = 0; r < 4; ++r)
          C[(size_t)(mb + r) * N + nb] = acc[i][j][r] + badd;
      } else {
        float* C = (float*)Cv;
#pragma unroll
        for (int r = 0; r < 4; ++r)
          atomicAdd(&C[(size_t)(mb + r) * N + nb], acc[i][j][r]);
      }
    }
  }
}

template <int MODE, bool PERMA>
__global__ __launch_bounds__(256) void gemm_nt_2d(
    const ushort_t* __restrict__ A, const ushort_t* __restrict__ BT,
    const float* __restrict__ bias, void* __restrict__ C, int N, int K) {
  gemm_body<MODE, PERMA>(A, BT, bias, C, N, K, blockIdx.y * 128,
                         blockIdx.x * 128, 0, K);
}

// KV conv GEMM: xpat[1024][12544] x WkvT[1024][12544]^T, split-K=14
// (K-chunk 896, 28 K-steps/block), 1-D grid 896, XCD decode mt=bl&7
// (A rows of one m-tile stay on one XCD L2).
__global__ __launch_bounds__(256) void gemm_kv_gl(
    const ushort_t* __restrict__ xpat, const ushort_t* __restrict__ WkvT,
    float* __restrict__ C) {
  const int bl = blockIdx.x;
  const int kbeg = (bl >> 6) * 896;
  gemm_body<2, false>(xpat, WkvT, (const float*)nullptr, C, 1024, 12544,
                      (bl & 7) * 128, ((bl >> 3) & 7) * 128, kbeg, kbeg + 896);
}

// ---------------------------------------------------------------------------
// Fallback (ws too small) kernels -- proven round-5/6 path, fp32 x inline cvt.
// ---------------------------------------------------------------------------
template <typename TA, typename TC>
__global__ __launch_bounds__(256) void gemm_mfma_nt(
    const TA* __restrict__ A, const ushort_t* __restrict__ BT,
    const float* __restrict__ bias, TC* __restrict__ C,
    int M, int N, int K, int has_bias) {
  __shared__ ushort_t lA[8 * 512];
  __shared__ ushort_t lB[8 * 512];
  const int t = threadIdx.x;
  const int m0 = blockIdx.y * 128;
  const int n0 = blockIdx.x * 128;
  const int lane = t & 63;
  const int wm = (t >> 6) >> 1, wn = (t >> 6) & 1;

  f32x4 acc[4][4] = {};

  const int sm = t >> 2;
  const int kq = t & 3;

  for (int k0 = 0; k0 < K; k0 += 32) {
#pragma unroll
    for (int h = 0; h < 2; ++h) {
      const int m = h * 64 + sm;
      const int off = (m >> 4) * 512 + (kq * 16 + (m & 15)) * 8;
      const ushort8v av = load8bf(A + (size_t)(m0 + m) * K + k0 + kq * 8);
      *(ushort8v*)&lA[off] = av;
      const ushort8v bv = load8bf(BT + (size_t)(n0 + m) * K + k0 + kq * 8);
      *(ushort8v*)&lB[off] = bv;
    }
    __syncthreads();
    short8v af[4], bf[4];
#pragma unroll
    for (int i = 0; i < 4; ++i) {
      af[i] = *(const short8v*)&lA[(wm * 4 + i) * 512 + lane * 8];
      bf[i] = *(const short8v*)&lB[(wn * 4 + i) * 512 + lane * 8];
    }
#pragma unroll
    for (int i = 0; i < 4; ++i)
#pragma unroll
      for (int j = 0; j < 4; ++j)
        acc[i][j] = __builtin_amdgcn_mfma_f32_16x16x32_bf16(
            af[i], bf[j], acc[i][j], 0, 0, 0);
    __syncthreads();
  }

  const int col = lane & 15, rq = (lane >> 4) * 4;
#pragma unroll
  for (int i = 0; i < 4; ++i) {
    const int mb = m0 + (wm * 4 + i) * 16 + rq;
#pragma unroll
    for (int j = 0; j < 4; ++j) {
      const int nb = n0 + (wn * 4 + j) * 16 + col;
      const float badd = has_bias ? bias[nb] : 0.f;
#pragma unroll
      for (int r = 0; r < 4; ++r)
        storeC(&C[(size_t)(mb + r) * N + nb], acc[i][j][r] + badd);
    }
  }
}

template <typename TA>
__global__ __launch_bounds__(256) void gemm_kv_mfma(
    const TA* __restrict__ x, const ushort_t* __restrict__ WkvT,
    float* __restrict__ C) {
  __shared__ ushort_t lA[8 * 512];
  __shared__ ushort_t lB[8 * 512];
  const int t = threadIdx.x;
  const int bl = blockIdx.x;
  const int m0 = (bl & 7) * 128;
  const int n0 = ((bl >> 3) & 7) * 128;
  const int kbeg = (bl >> 6) * 896;
  const int lane = t & 63;
  const int wm = (t >> 6) >> 1, wn = (t >> 6) & 1;

  f32x4 acc[4][4] = {};

  const int sm = t >> 2;
  const int kq = t & 3;

  for (int k0 = kbeg; k0 < kbeg + 896; k0 += 32) {
#pragma unroll
    for (int h = 0; h < 2; ++h) {
      const int m = h * 64 + sm;
      const int off = (m >> 4) * 512 + (kq * 16 + (m & 15)) * 8;
      const int gm = m0 + m;
      const int b = gm >> 6, ty = (gm >> 3) & 7, tx = gm & 7;
      const int k = k0 + kq * 8;
      const int patch = k >> 8;
      const int c = k & 255;
      const int dy = (patch * 37) >> 8;
      const int dx = patch - dy * 7;
      const int pix = b * 3136 + (ty * 7 + dy) * 56 + (tx * 7 + dx);
      const ushort8v av = load8bf(x + (size_t)pix * 256 + c);
      *(ushort8v*)&lA[off] = av;
      const ushort8v bv =
          load8bf(WkvT + (size_t)(n0 + m) * 12544 + k0 + kq * 8);
      *(ushort8v*)&lB[off] = bv;
    }
    __syncthreads();
    short8v af[4], bf[4];
#pragma unroll
    for (int i = 0; i < 4; ++i) {
      af[i] = *(const short8v*)&lA[(wm * 4 + i) * 512 + lane * 8];
      bf[i] = *(const short8v*)&lB[(wn * 4 + i) * 512 + lane * 8];
    }
#pragma unroll
    for (int i = 0; i < 4; ++i)
#pragma unroll
      for (int j = 0; j < 4; ++j)
        acc[i][j] = __builtin_amdgcn_mfma_f32_16x16x32_bf16(
            af[i], bf[j], acc[i][j], 0, 0, 0);
    __syncthreads();
  }

  const int col = lane & 15, rq = (lane >> 4) * 4;
#pragma unroll
  for (int i = 0; i < 4; ++i) {
    const int mb = m0 + (wm * 4 + i) * 16 + rq;
#pragma unroll
    for (int j = 0; j < 4; ++j) {
      const int nb = n0 + (wn * 4 + j) * 16 + col;
#pragma unroll
      for (int r = 0; r < 4; ++r)
        atomicAdd(&C[(size_t)(mb + r) * 1024 + nb], acc[i][j][r]);
    }
  }
}

// ---------------------------------------------------------------------------
// MFMA attention, in-place on bf16 qbuf.  (round-6 proven, unchanged)
// ---------------------------------------------------------------------------
__global__ __launch_bounds__(256) void attn_mfma(
    ushort_t* __restrict__ qo, const ushort_t* __restrict__ kvb) {
  __shared__ ushort_t VT[64][72];
  __shared__ ushort_t P[4][64][72];
  const int t = threadIdx.x;
  const int lane = t & 63;
  const int w = t >> 6;
  const int bh = blockIdx.y;
  const int b = bh >> 3, h = bh & 7;
  const ushort_t* kvp = kvb + (size_t)(b * 64) * 1024 + h * 64;

  for (int i = t; i < 512; i += 256) {
    const int key = i >> 3, d0 = (i & 7) * 8;
    const ushort8v v = *(const ushort8v*)(kvp + (size_t)key * 1024 + 512 + d0);
#pragma unroll
    for (int jj = 0; jj < 8; ++jj) VT[d0 + jj][key] = v[jj];
  }
  __syncthreads();

  const int q0_raw = blockIdx.x * 256 + w * 64;
  const bool valid = q0_raw < 3136;
  const int q0 = valid ? q0_raw : 3072;
  const size_t qbase = ((size_t)b * 3136 + q0) * 512 + h * 64;

  const int lm = lane & 15, quad = lane >> 4;

  short8v qf[4][2], kf[4][2];
#pragma unroll
  for (int i = 0; i < 4; ++i)
#pragma unroll
    for (int s = 0; s < 2; ++s) {
      qf[i][s] = *(const short8v*)(qo + qbase + (size_t)(16 * i + lm) * 512 +
                                   32 * s + quad * 8);
      kf[i][s] = *(const short8v*)(kvp + (size_t)(16 * i + lm) * 1024 +
                                   32 * s + quad * 8);
    }

  f32x4 sa[4][4];
#pragma unroll
  for (int i = 0; i < 4; ++i)
#pragma unroll
    for (int j = 0; j < 4; ++j) {
      f32x4 z = {};
      z = __builtin_amdgcn_mfma_f32_16x16x32_bf16(qf[i][0], kf[j][0], z, 0, 0, 0);
      sa[i][j] = __builtin_amdgcn_mfma_f32_16x16x32_bf16(qf[i][1], kf[j][1], z, 0, 0, 0);
    }

  float l[4][4];
#pragma unroll
  for (int i = 0; i < 4; ++i)
#pragma unroll
    for (int r = 0; r < 4; ++r) {
      float m = fmaxf(fmaxf(sa[i][0][r], sa[i][1][r]),
                      fmaxf(sa[i][2][r], sa[i][3][r]));
#pragma unroll
      for (int off = 1; off < 16; off <<= 1) m = fmaxf(m, __shfl_xor(m, off));
      float sum = 0.f;
#pragma unroll
      for (int j = 0; j < 4; ++j) {
        const float p = __expf(0.125f * (sa[i][j][r] - m));
        sa[i][j][r] = p;
        sum += p;
      }
#pragma unroll
      for (int off = 1; off < 16; off <<= 1) sum += __shfl_xor(sum, off);
      l[i][r] = sum;
    }

#pragma unroll
  for (int i = 0; i < 4; ++i) {
    const int row = 16 * i + quad * 4;
#pragma unroll
    for (int j = 0; j < 4; ++j) {
      const int col = 16 * j + lm;
#pragma unroll
      for (int r = 0; r < 4; ++r) P[w][row + r][col] = f2bf(sa[i][j][r]);
    }
  }
  __syncthreads();

  short8v vf[4][2];
#pragma unroll
  for (int jn = 0; jn < 4; ++jn)
#pragma unroll
    for (int s2 = 0; s2 < 2; ++s2)
      vf[jn][s2] = *(const short8v*)&VT[16 * jn + lm][32 * s2 + quad * 8];

  f32x4 oa[4][4];
#pragma unroll
  for (int i = 0; i < 4; ++i) {
    const short8v pf0 = *(const short8v*)&P[w][16 * i + lm][quad * 8];
    const short8v pf1 = *(const short8v*)&P[w][16 * i + lm][32 + quad * 8];
#pragma unroll
    for (int jn = 0; jn < 4; ++jn) {
      f32x4 z = {};
      z = __builtin_amdgcn_mfma_f32_16x16x32_bf16(pf0, vf[jn][0], z, 0, 0, 0);
      oa[i][jn] = __builtin_amdgcn_mfma_f32_16x16x32_bf16(pf1, vf[jn][1], z, 0, 0, 0);
    }
  }

  if (valid) {
#pragma unroll
    for (int i = 0; i < 4; ++i) {
#pragma unroll
      for (int r = 0; r < 4; ++r) {
        const float inv = 1.f / l[i][r];
        const size_t rowoff = qbase + (size_t)(16 * i + quad * 4 + r) * 512;
#pragma unroll
        for (int jn = 0; jn < 4; ++jn)
          qo[rowoff + 16 * jn + lm] = f2bf(oa[i][jn][r] * inv);
      }
    }
  }
}

// ---------------------------------------------------------------------------
// Workspace (bytes), preferred layout total 109,576,192 (unchanged):
//   qbuf  @ 0        : 50176*512*2  = 51,380,224  bf16 (q, then attn out)
//   kvbuf @ 51380224 : 1024*1024*4  =  4,194,304  fp32 (atomic split-K)
//   WkvT  @ 55574528 : 1024*12544*2 = 25,690,112  bf16
//   WqT   @ 81264640 : 512*256*2    =     262,144 bf16
//   WoT   @ 81526784 : 256*512*2    =     262,144 bf16
//   kvbf  @ 81788928 : 1024*1024*2  =  2,097,152  bf16
//   xpat  @ 83886080 : 12845056*2   = 25,690,112  bf16 patch-major im2col
// Fallback (< 110 MB): round-6 path (fp32 x with inline cvt), proven.
// ---------------------------------------------------------------------------
extern "C" void kernel_launch(void* const* d_in, const int* in_sizes, int n_in,
                              void* d_out, int out_size, void* d_ws,
                              size_t ws_size, hipStream_t stream) {
  const float* x = (const float*)d_in[0];
  const float* Wq = (const float*)d_in[1];
  const float* Wkv = (const float*)d_in[2];
  const float* Wo = (const float*)d_in[3];
  const float* bo = (const float*)d_in[4];
  float* out = (float*)d_out;

  char* ws = (char*)d_ws;
  ushort_t* qbuf = (ushort_t*)(ws);
  float* kvbuf = (float*)(ws + 51380224);
  ushort_t* WkvT = (ushort_t*)(ws + 55574528);
  ushort_t* WqT = (ushort_t*)(ws + 81264640);
  ushort_t* WoT = (ushort_t*)(ws + 81526784);
  ushort_t* kvbf = (ushort_t*)(ws + 81788928);
  ushort_t* xpat = (ushort_t*)(ws + 83886080);
  const bool use_fast = ws_size >= 109576192u;

  // 0) weight transposes + bf16 cvt; kvbuf zero for atomic split-K
  hipLaunchKernelGGL(transpose_cvt, dim3(16, 8), dim3(256), 0, stream, Wq, WqT,
                     256, 512);
  hipLaunchKernelGGL(transpose_cvt, dim3(32, 392), dim3(256), 0, stream, Wkv,
                     WkvT, 12544, 1024);
  hipLaunchKernelGGL(transpose_cvt, dim3(8, 16), dim3(256), 0, stream, Wo, WoT,
                     512, 256);
  hipMemsetAsync(kvbuf, 0, 1024 * 1024 * 4, stream);

  if (use_fast) {
    // 0b) x -> bf16 patch-major im2col pack (pure permutation, same bytes)
    hipLaunchKernelGGL(cvt_im2col, dim3(6272), dim3(256), 0, stream, x, xpat);
    // 1) Q projection; A rows read from xpat via per-thread row perm
    hipLaunchKernelGGL((gemm_nt_2d<0, true>), dim3(4, 392), dim3(256), 0,
                       stream, xpat, WqT, (const float*)nullptr, qbuf, 512,
                       256);
    // 2) KV conv GEMM, reg-staged dist-2 pipeline + LDS swizzle, split-K=14
    hipLaunchKernelGGL(gemm_kv_gl, dim3(896), dim3(256), 0, stream, xpat,
                       WkvT, kvbuf);
    hipLaunchKernelGGL(cvt_f32_bf16, dim3(1024), dim3(256), 0, stream, kvbuf,
                       kvbf);
    // 3) MFMA attention, in-place on qbuf
    hipLaunchKernelGGL(attn_mfma, dim3(13, 128), dim3(256), 0, stream, qbuf,
                       kvbf);
    // 4) output projection + bias
    hipLaunchKernelGGL((gemm_nt_2d<1, false>), dim3(2, 392), dim3(256), 0,
                       stream, qbuf, WoT, bo, out, 256, 512);
  } else {
    hipLaunchKernelGGL((gemm_mfma_nt<float, ushort_t>), dim3(4, 392),
                       dim3(256), 0, stream, x, WqT, (const float*)nullptr,
                       qbuf, 50176, 512, 256, 0);
    hipLaunchKernelGGL((gemm_kv_mfma<float>), dim3(896), dim3(256), 0, stream,
                       x, WkvT, kvbuf);
    hipLaunchKernelGGL(cvt_f32_bf16, dim3(1024), dim3(256), 0, stream, kvbuf,
                       kvbf);
    hipLaunchKernelGGL(attn_mfma, dim3(13, 128), dim3(256), 0, stream, qbuf,
                       kvbf);
    hipLaunchKernelGGL((gemm_mfma_nt<ushort_t, float>), dim3(2, 392),
                       dim3(256), 0, stream, qbuf, WoT, bo, out, 50176, 256,
                       512, 1);
  }
}

// Round 10
// 333.545 us; speedup vs baseline: 1.0575x; 1.0575x over previous
//
#include <hip/hip_runtime.h>
#include <stdint.h>

typedef unsigned short ushort_t;
typedef __attribute__((ext_vector_type(8))) unsigned short ushort8v;
typedef __attribute__((ext_vector_type(8))) short short8v;  // 8 bf16 = 4 VGPRs
typedef __attribute__((ext_vector_type(4))) float f32x4;    // MFMA C/D frag

__device__ __forceinline__ float bf2f(ushort_t u) {
  union { unsigned int i; float f; } v;
  v.i = ((unsigned int)u) << 16;
  return v.f;
}
__device__ __forceinline__ ushort_t f2bf(float f) {
  union { float f; unsigned int i; } v;
  v.f = f;
  unsigned int r = v.i + 0x7FFFu + ((v.i >> 16) & 1u);  // RNE
  return (ushort_t)(r >> 16);
}

// Load 8 elements as bf16 bit-pattern vector (cvt if source is fp32).
__device__ __forceinline__ ushort8v load8bf(const ushort_t* __restrict__ p) {
  return *(const ushort8v*)p;
}
__device__ __forceinline__ ushort8v load8bf(const float* __restrict__ p) {
  const float4 a = *(const float4*)p;
  const float4 b = *(const float4*)(p + 4);
  ushort8v r;
  r[0] = f2bf(a.x); r[1] = f2bf(a.y); r[2] = f2bf(a.z); r[3] = f2bf(a.w);
  r[4] = f2bf(b.x); r[5] = f2bf(b.y); r[6] = f2bf(b.z); r[7] = f2bf(b.w);
  return r;
}
__device__ __forceinline__ void storeC(float* p, float v) { *p = v; }
__device__ __forceinline__ void storeC(ushort_t* p, float v) { *p = f2bf(v); }

// pixel index (b,y,x layout, 56x56) -> element offset of that 256-chan row
// inside the patch-major packed tensor xpat[1024][12544].
// (7x7 stride-7 conv: im2col is a pure row permutation.)
__device__ __forceinline__ size_t pp_off(unsigned g) {
  const unsigned b = g / 3136u;
  const unsigned r = g - b * 3136u;
  const unsigned y = r / 56u, xx = r - y * 56u;
  const unsigned ty = y / 7u, dy = y - ty * 7u;
  const unsigned tx = xx / 7u, dx = xx - tx * 7u;
  return ((size_t)((b * 64u + ty * 8u + tx) * 49u + dy * 7u + dx)) << 8;
}

// ---------------------------------------------------------------------------
// Transpose + fp32->bf16: W[K][N] -> WT[N][K].  32x32 tiles, 256 threads.
// ---------------------------------------------------------------------------
__global__ __launch_bounds__(256) void transpose_cvt(
    const float* __restrict__ W, ushort_t* __restrict__ WT, int K, int N) {
  __shared__ float tile[32][33];
  const int t = threadIdx.x;
  const int k0 = blockIdx.y * 32;
  const int n0 = blockIdx.x * 32;
  {
    const int r = t >> 3, c4 = (t & 7) * 4;
    const float4 v = *(const float4*)(W + (size_t)(k0 + r) * N + n0 + c4);
    tile[r][c4] = v.x; tile[r][c4 + 1] = v.y;
    tile[r][c4 + 2] = v.z; tile[r][c4 + 3] = v.w;
  }
  __syncthreads();
  {
    const int rn = t >> 3, ck = (t & 7) * 4;
    union { ushort_t u[4]; uint2 v; } o;
#pragma unroll
    for (int j = 0; j < 4; ++j) o.u[j] = f2bf(tile[ck + j][rn]);
    *(uint2*)(WT + (size_t)(n0 + rn) * K + k0 + ck) = o.v;
  }
}

// ---------------------------------------------------------------------------
// fp32 -> bf16 bulk convert (n % 1024 == 0), 4 elems/thread.
// ---------------------------------------------------------------------------
__global__ __launch_bounds__(256) void cvt_f32_bf16(
    const float* __restrict__ in, ushort_t* __restrict__ out) {
  const int i = (blockIdx.x * 256 + threadIdx.x) * 4;
  const float4 v = *(const float4*)(in + i);
  union { ushort_t u[4]; uint2 q; } o;
  o.u[0] = f2bf(v.x); o.u[1] = f2bf(v.y);
  o.u[2] = f2bf(v.z); o.u[3] = f2bf(v.w);
  *(uint2*)(out + i) = o.q;
}

// ---------------------------------------------------------------------------
// x [50176][256] fp32 -> xpat [1024][12544] bf16, patch-major (im2col packed).
// 8 elems/thread; reads coalesced, writes in 512B row chunks.
// ---------------------------------------------------------------------------
__global__ __launch_bounds__(256) void cvt_im2col(
    const float* __restrict__ x, ushort_t* __restrict__ xp) {
  const int e = (blockIdx.x * 256 + threadIdx.x) * 8;
  const unsigned p = ((unsigned)e) >> 8;
  const int c = e & 255;
  const float4 a = *(const float4*)(x + e);
  const float4 b = *(const float4*)(x + e + 4);
  ushort8v o;
  o[0] = f2bf(a.x); o[1] = f2bf(a.y); o[2] = f2bf(a.z); o[3] = f2bf(a.w);
  o[4] = f2bf(b.x); o[5] = f2bf(b.y); o[6] = f2bf(b.z); o[7] = f2bf(b.w);
  *(ushort8v*)(xp + pp_off(p) + c) = o;
}

// ---------------------------------------------------------------------------
// Unified MFMA NT GEMM body, REG-STAGED pipeline, per-kernel DEPTH.
// Round-9 lesson: prefetch distance 2 helps ONLY long K-chunks (kv nst=28:
// 83->79.5us) and hurts short ones (Q nst=8 / O nst=16: prologue fill/drain
// + 2x code = non-kv +12us).  DEPTH is now a template param: kv=2, Q/O=1.
// Both paths share the r8-proven pieces: r6 thread->global map (quad-
// contiguous reads, 2100+ GB/s) + LDS XOR swizzle (write conflicts
// 9.6M->3.2M).  DEPTH=1 loop == r8 body bit-for-bit; DEPTH=2 == r9 body.
// MODE: 0 = bf16 store, no bias; 1 = fp32 store + bias; 2 = fp32 atomicAdd.
// PERMA: A rows indexed through pp_off (loop-invariant, computed once).
// ---------------------------------------------------------------------------
template <int MODE, bool PERMA, int DEPTH>
__device__ __forceinline__ void gemm_body(
    const ushort_t* __restrict__ A, const ushort_t* __restrict__ BT,
    const float* __restrict__ bias, void* __restrict__ Cv,
    int N, int K, int m0, int n0, int kbeg, int kend) {
  __shared__ ushort_t lA[2][4096];
  __shared__ ushort_t lB[2][4096];
  const int t = threadIdx.x;
  const int lane = t & 63;
  const int wv = t >> 6;
  const int wm = wv >> 1, wn = wv & 1;
  const int sm = t >> 2;   // row owner (r6 map: quad-contiguous global reads)
  const int kq = t & 3;    // 16B chunk within 32-wide K tile

  // LDS slot swizzle (r8 proven).  wslot/rdsw are loop-invariant.
  const int row16 = sm & 15;
  const int wslot = kq * 16 + (row16 ^ kq);
  const int rdsw = (lane ^ ((lane >> 4) & 3)) * 8;  // shorts

  const ushort_t* aR[2];
  const ushort_t* bR[2];
  int off[2];
#pragma unroll
  for (int h = 0; h < 2; ++h) {
    const int m = h * 64 + sm;  // 0..127
    off[h] = (h * 4 + wv) * 512 + wslot * 8;
    size_t aoff;
    if (PERMA)
      aoff = pp_off((unsigned)(m0 + m));
    else
      aoff = (size_t)(m0 + m) * K;
    aR[h] = A + aoff + kq * 8;
    bR[h] = BT + (size_t)(n0 + m) * K + kq * 8;
  }

  f32x4 acc[4][4] = {};
  const int nst = (kend - kbeg) >> 5;  // K-steps, even for all users

  if constexpr (DEPTH == 1) {
    // ---- r8-proven 2-phase, distance-1 (best for nst <= 16) ----
    ushort8v av[2], bv[2];
#pragma unroll
    for (int h = 0; h < 2; ++h) {
      av[h] = *(const ushort8v*)(aR[h] + kbeg);
      bv[h] = *(const ushort8v*)(bR[h] + kbeg);
    }
#pragma unroll
    for (int h = 0; h < 2; ++h) {
      *(ushort8v*)&lA[0][off[h]] = av[h];
      *(ushort8v*)&lB[0][off[h]] = bv[h];
    }
    __syncthreads();

    for (int st = 0; st < nst; ++st) {
      const int cur = st & 1;
      if (st + 1 < nst) {  // issue next tile's loads early (T14)
        const int nk = kbeg + (st + 1) * 32;
#pragma unroll
        for (int h = 0; h < 2; ++h) {
          av[h] = *(const ushort8v*)(aR[h] + nk);
          bv[h] = *(const ushort8v*)(bR[h] + nk);
        }
      }
      short8v af[4], bfr[4];
#pragma unroll
      for (int i = 0; i < 4; ++i) {
        af[i] = *(const short8v*)&lA[cur][(wm * 4 + i) * 512 + rdsw];
        bfr[i] = *(const short8v*)&lB[cur][(wn * 4 + i) * 512 + rdsw];
      }
#pragma unroll
      for (int i = 0; i < 4; ++i)
#pragma unroll
        for (int j = 0; j < 4; ++j)
          acc[i][j] = __builtin_amdgcn_mfma_f32_16x16x32_bf16(
              af[i], bfr[j], acc[i][j], 0, 0, 0);

      if (st + 1 < nst) {  // write-late into the other buffer
#pragma unroll
        for (int h = 0; h < 2; ++h) {
          *(ushort8v*)&lA[cur ^ 1][off[h]] = av[h];
          *(ushort8v*)&lB[cur ^ 1][off[h]] = bv[h];
        }
      }
      __syncthreads();
    }
  } else {
    // ---- r9-proven distance-2 (best for long K-chunks, nst >= 28) ----
    ushort8v avA0, avA1, bvA0, bvA1;
    ushort8v avB0, avB1, bvB0, bvB1;

    {
      ushort8v a0 = *(const ushort8v*)(aR[0] + kbeg);
      ushort8v a1 = *(const ushort8v*)(aR[1] + kbeg);
      ushort8v b0 = *(const ushort8v*)(bR[0] + kbeg);
      ushort8v b1 = *(const ushort8v*)(bR[1] + kbeg);
      *(ushort8v*)&lA[0][off[0]] = a0;
      *(ushort8v*)&lA[0][off[1]] = a1;
      *(ushort8v*)&lB[0][off[0]] = b0;
      *(ushort8v*)&lB[0][off[1]] = b1;
    }
    if (1 < nst) {
      const int nk = kbeg + 32;
      avB0 = *(const ushort8v*)(aR[0] + nk);
      avB1 = *(const ushort8v*)(aR[1] + nk);
      bvB0 = *(const ushort8v*)(bR[0] + nk);
      bvB1 = *(const ushort8v*)(bR[1] + nk);
    }
    if (2 < nst) {
      const int nk = kbeg + 64;
      avA0 = *(const ushort8v*)(aR[0] + nk);
      avA1 = *(const ushort8v*)(aR[1] + nk);
      bvA0 = *(const ushort8v*)(bR[0] + nk);
      bvA1 = *(const ushort8v*)(bR[1] + nk);
    }
    __syncthreads();

    for (int st = 0; st < nst; st += 2) {
      if (st + 1 < nst) {
        *(ushort8v*)&lA[1][off[0]] = avB0;
        *(ushort8v*)&lA[1][off[1]] = avB1;
        *(ushort8v*)&lB[1][off[0]] = bvB0;
        *(ushort8v*)&lB[1][off[1]] = bvB1;
      }
      if (st + 3 < nst) {
        const int nk = kbeg + (st + 3) * 32;
        avB0 = *(const ushort8v*)(aR[0] + nk);
        avB1 = *(const ushort8v*)(aR[1] + nk);
        bvB0 = *(const ushort8v*)(bR[0] + nk);
        bvB1 = *(const ushort8v*)(bR[1] + nk);
      }
      {
        short8v af[4], bfr[4];
#pragma unroll
        for (int i = 0; i < 4; ++i) {
          af[i] = *(const short8v*)&lA[0][(wm * 4 + i) * 512 + rdsw];
          bfr[i] = *(const short8v*)&lB[0][(wn * 4 + i) * 512 + rdsw];
        }
#pragma unroll
        for (int i = 0; i < 4; ++i)
#pragma unroll
          for (int j = 0; j < 4; ++j)
            acc[i][j] = __builtin_amdgcn_mfma_f32_16x16x32_bf16(
                af[i], bfr[j], acc[i][j], 0, 0, 0);
      }
      __syncthreads();
      if (st + 1 >= nst) break;

      if (st + 2 < nst) {
        *(ushort8v*)&lA[0][off[0]] = avA0;
        *(ushort8v*)&lA[0][off[1]] = avA1;
        *(ushort8v*)&lB[0][off[0]] = bvA0;
        *(ushort8v*)&lB[0][off[1]] = bvA1;
      }
      if (st + 4 < nst) {
        const int nk = kbeg + (st + 4) * 32;
        avA0 = *(const ushort8v*)(aR[0] + nk);
        avA1 = *(const ushort8v*)(aR[1] + nk);
        bvA0 = *(const ushort8v*)(bR[0] + nk);
        bvA1 = *(const ushort8v*)(bR[1] + nk);
      }
      {
        short8v af[4], bfr[4];
#pragma unroll
        for (int i = 0; i < 4; ++i) {
          af[i] = *(const short8v*)&lA[1][(wm * 4 + i) * 512 + rdsw];
          bfr[i] = *(const short8v*)&lB[1][(wn * 4 + i) * 512 + rdsw];
        }
#pragma unroll
        for (int i = 0; i < 4; ++i)
#pragma unroll
          for (int j = 0; j < 4; ++j)
            acc[i][j] = __builtin_amdgcn_mfma_f32_16x16x32_bf16(
                af[i], bfr[j], acc[i][j], 0, 0, 0);
      }
      __syncthreads();
    }
  }

  const int col = lane & 15, rq = (lane >> 4) * 4;
#pragma unroll
  for (int i = 0; i < 4; ++i) {
    const int mb = m0 + (wm * 4 + i) * 16 + rq;
#pragma unroll
    for (int j = 0; j < 4; ++j) {
      const int nb = n0 + (wn * 4 + j) * 16 + col;
      if (MODE == 0) {
        ushort_t* C = (ushort_t*)Cv;
#pragma unroll
        for (int r = 0; r < 4; ++r)
          C[(size_t)(mb + r) * N + nb] = f2bf(acc[i][j][r]);
      } else if (MODE == 1) {
        float* C = (float*)Cv;
        const float badd = bias[nb];
#pragma unroll
        for (int r = 0; r < 4; ++r)
          C[(size_t)(mb + r) * N + nb] = acc[i][j][r] + badd;
      } else {
        float* C = (float*)Cv;
#pragma unroll
        for (int r = 0; r < 4; ++r)
          atomicAdd(&C[(size_t)(mb + r) * N + nb], acc[i][j][r]);
      }
    }
  }
}

template <int MODE, bool PERMA>
__global__ __launch_bounds__(256) void gemm_nt_2d(
    const ushort_t* __restrict__ A, const ushort_t* __restrict__ BT,
    const float* __restrict__ bias, void* __restrict__ C, int N, int K) {
  gemm_body<MODE, PERMA, 1>(A, BT, bias, C, N, K, blockIdx.y * 128,
                            blockIdx.x * 128, 0, K);
}

// KV conv GEMM: xpat[1024][12544] x WkvT[1024][12544]^T, split-K=14
// (K-chunk 896, 28 K-steps/block), 1-D grid 896, XCD decode mt=bl&7
// (A rows of one m-tile stay on one XCD L2).  DEPTH=2 (r9: 83->79.5us).
__global__ __launch_bounds__(256) void gemm_kv_gl(
    const ushort_t* __restrict__ xpat, const ushort_t* __restrict__ WkvT,
    float* __restrict__ C) {
  const int bl = blockIdx.x;
  const int kbeg = (bl >> 6) * 896;
  gemm_body<2, false, 2>(xpat, WkvT, (const float*)nullptr, C, 1024, 12544,
                         (bl & 7) * 128, ((bl >> 3) & 7) * 128, kbeg,
                         kbeg + 896);
}

// ---------------------------------------------------------------------------
// Fallback (ws too small) kernels -- proven round-5/6 path, fp32 x inline cvt.
// ---------------------------------------------------------------------------
template <typename TA, typename TC>
__global__ __launch_bounds__(256) void gemm_mfma_nt(
    const TA* __restrict__ A, const ushort_t* __restrict__ BT,
    const float* __restrict__ bias, TC* __restrict__ C,
    int M, int N, int K, int has_bias) {
  __shared__ ushort_t lA[8 * 512];
  __shared__ ushort_t lB[8 * 512];
  const int t = threadIdx.x;
  const int m0 = blockIdx.y * 128;
  const int n0 = blockIdx.x * 128;
  const int lane = t & 63;
  const int wm = (t >> 6) >> 1, wn = (t >> 6) & 1;

  f32x4 acc[4][4] = {};

  const int sm = t >> 2;
  const int kq = t & 3;

  for (int k0 = 0; k0 < K; k0 += 32) {
#pragma unroll
    for (int h = 0; h < 2; ++h) {
      const int m = h * 64 + sm;
      const int off = (m >> 4) * 512 + (kq * 16 + (m & 15)) * 8;
      const ushort8v av = load8bf(A + (size_t)(m0 + m) * K + k0 + kq * 8);
      *(ushort8v*)&lA[off] = av;
      const ushort8v bv = load8bf(BT + (size_t)(n0 + m) * K + k0 + kq * 8);
      *(ushort8v*)&lB[off] = bv;
    }
    __syncthreads();
    short8v af[4], bf[4];
#pragma unroll
    for (int i = 0; i < 4; ++i) {
      af[i] = *(const short8v*)&lA[(wm * 4 + i) * 512 + lane * 8];
      bf[i] = *(const short8v*)&lB[(wn * 4 + i) * 512 + lane * 8];
    }
#pragma unroll
    for (int i = 0; i < 4; ++i)
#pragma unroll
      for (int j = 0; j < 4; ++j)
        acc[i][j] = __builtin_amdgcn_mfma_f32_16x16x32_bf16(
            af[i], bf[j], acc[i][j], 0, 0, 0);
    __syncthreads();
  }

  const int col = lane & 15, rq = (lane >> 4) * 4;
#pragma unroll
  for (int i = 0; i < 4; ++i) {
    const int mb = m0 + (wm * 4 + i) * 16 + rq;
#pragma unroll
    for (int j = 0; j < 4; ++j) {
      const int nb = n0 + (wn * 4 + j) * 16 + col;
      const float badd = has_bias ? bias[nb] : 0.f;
#pragma unroll
      for (int r = 0; r < 4; ++r)
        storeC(&C[(size_t)(mb + r) * N + nb], acc[i][j][r] + badd);
    }
  }
}

template <typename TA>
__global__ __launch_bounds__(256) void gemm_kv_mfma(
    const TA* __restrict__ x, const ushort_t* __restrict__ WkvT,
    float* __restrict__ C) {
  __shared__ ushort_t lA[8 * 512];
  __shared__ ushort_t lB[8 * 512];
  const int t = threadIdx.x;
  const int bl = blockIdx.x;
  const int m0 = (bl & 7) * 128;
  const int n0 = ((bl >> 3) & 7) * 128;
  const int kbeg = (bl >> 6) * 896;
  const int lane = t & 63;
  const int wm = (t >> 6) >> 1, wn = (t >> 6) & 1;

  f32x4 acc[4][4] = {};

  const int sm = t >> 2;
  const int kq = t & 3;

  for (int k0 = kbeg; k0 < kbeg + 896; k0 += 32) {
#pragma unroll
    for (int h = 0; h < 2; ++h) {
      const int m = h * 64 + sm;
      const int off = (m >> 4) * 512 + (kq * 16 + (m & 15)) * 8;
      const int gm = m0 + m;
      const int b = gm >> 6, ty = (gm >> 3) & 7, tx = gm & 7;
      const int k = k0 + kq * 8;
      const int patch = k >> 8;
      const int c = k & 255;
      const int dy = (patch * 37) >> 8;
      const int dx = patch - dy * 7;
      const int pix = b * 3136 + (ty * 7 + dy) * 56 + (tx * 7 + dx);
      const ushort8v av = load8bf(x + (size_t)pix * 256 + c);
      *(ushort8v*)&lA[off] = av;
      const ushort8v bv =
          load8bf(WkvT + (size_t)(n0 + m) * 12544 + k0 + kq * 8);
      *(ushort8v*)&lB[off] = bv;
    }
    __syncthreads();
    short8v af[4], bf[4];
#pragma unroll
    for (int i = 0; i < 4; ++i) {
      af[i] = *(const short8v*)&lA[(wm * 4 + i) * 512 + lane * 8];
      bf[i] = *(const short8v*)&lB[(wn * 4 + i) * 512 + lane * 8];
    }
#pragma unroll
    for (int i = 0; i < 4; ++i)
#pragma unroll
      for (int j = 0; j < 4; ++j)
        acc[i][j] = __builtin_amdgcn_mfma_f32_16x16x32_bf16(
            af[i], bf[j], acc[i][j], 0, 0, 0);
    __syncthreads();
  }

  const int col = lane & 15, rq = (lane >> 4) * 4;
#pragma unroll
  for (int i = 0; i < 4; ++i) {
    const int mb = m0 + (wm * 4 + i) * 16 + rq;
#pragma unroll
    for (int j = 0; j < 4; ++j) {
      const int nb = n0 + (wn * 4 + j) * 16 + col;
#pragma unroll
      for (int r = 0; r < 4; ++r)
        atomicAdd(&C[(size_t)(mb + r) * 1024 + nb], acc[i][j][r]);
    }
  }
}

// ---------------------------------------------------------------------------
// MFMA attention, in-place on bf16 qbuf.  (round-6 proven, unchanged)
// ---------------------------------------------------------------------------
__global__ __launch_bounds__(256) void attn_mfma(
    ushort_t* __restrict__ qo, const ushort_t* __restrict__ kvb) {
  __shared__ ushort_t VT[64][72];
  __shared__ ushort_t P[4][64][72];
  const int t = threadIdx.x;
  const int lane = t & 63;
  const int w = t >> 6;
  const int bh = blockIdx.y;
  const int b = bh >> 3, h = bh & 7;
  const ushort_t* kvp = kvb + (size_t)(b * 64) * 1024 + h * 64;

  for (int i = t; i < 512; i += 256) {
    const int key = i >> 3, d0 = (i & 7) * 8;
    const ushort8v v = *(const ushort8v*)(kvp + (size_t)key * 1024 + 512 + d0);
#pragma unroll
    for (int jj = 0; jj < 8; ++jj) VT[d0 + jj][key] = v[jj];
  }
  __syncthreads();

  const int q0_raw = blockIdx.x * 256 + w * 64;
  const bool valid = q0_raw < 3136;
  const int q0 = valid ? q0_raw : 3072;
  const size_t qbase = ((size_t)b * 3136 + q0) * 512 + h * 64;

  const int lm = lane & 15, quad = lane >> 4;

  short8v qf[4][2], kf[4][2];
#pragma unroll
  for (int i = 0; i < 4; ++i)
#pragma unroll
    for (int s = 0; s < 2; ++s) {
      qf[i][s] = *(const short8v*)(qo + qbase + (size_t)(16 * i + lm) * 512 +
                                   32 * s + quad * 8);
      kf[i][s] = *(const short8v*)(kvp + (size_t)(16 * i + lm) * 1024 +
                                   32 * s + quad * 8);
    }

  f32x4 sa[4][4];
#pragma unroll
  for (int i = 0; i < 4; ++i)
#pragma unroll
    for (int j = 0; j < 4; ++j) {
      f32x4 z = {};
      z = __builtin_amdgcn_mfma_f32_16x16x32_bf16(qf[i][0], kf[j][0], z, 0, 0, 0);
      sa[i][j] = __builtin_amdgcn_mfma_f32_16x16x32_bf16(qf[i][1], kf[j][1], z, 0, 0, 0);
    }

  float l[4][4];
#pragma unroll
  for (int i = 0; i < 4; ++i)
#pragma unroll
    for (int r = 0; r < 4; ++r) {
      float m = fmaxf(fmaxf(sa[i][0][r], sa[i][1][r]),
                      fmaxf(sa[i][2][r], sa[i][3][r]));
#pragma unroll
      for (int off = 1; off < 16; off <<= 1) m = fmaxf(m, __shfl_xor(m, off));
      float sum = 0.f;
#pragma unroll
      for (int j = 0; j < 4; ++j) {
        const float p = __expf(0.125f * (sa[i][j][r] - m));
        sa[i][j][r] = p;
        sum += p;
      }
#pragma unroll
      for (int off = 1; off < 16; off <<= 1) sum += __shfl_xor(sum, off);
      l[i][r] = sum;
    }

#pragma unroll
  for (int i = 0; i < 4; ++i) {
    const int row = 16 * i + quad * 4;
#pragma unroll
    for (int j = 0; j < 4; ++j) {
      const int col = 16 * j + lm;
#pragma unroll
      for (int r = 0; r < 4; ++r) P[w][row + r][col] = f2bf(sa[i][j][r]);
    }
  }
  __syncthreads();

  short8v vf[4][2];
#pragma unroll
  for (int jn = 0; jn < 4; ++jn)
#pragma unroll
    for (int s2 = 0; s2 < 2; ++s2)
      vf[jn][s2] = *(const short8v*)&VT[16 * jn + lm][32 * s2 + quad * 8];

  f32x4 oa[4][4];
#pragma unroll
  for (int i = 0; i < 4; ++i) {
    const short8v pf0 = *(const short8v*)&P[w][16 * i + lm][quad * 8];
    const short8v pf1 = *(const short8v*)&P[w][16 * i + lm][32 + quad * 8];
#pragma unroll
    for (int jn = 0; jn < 4; ++jn) {
      f32x4 z = {};
      z = __builtin_amdgcn_mfma_f32_16x16x32_bf16(pf0, vf[jn][0], z, 0, 0, 0);
      oa[i][jn] = __builtin_amdgcn_mfma_f32_16x16x32_bf16(pf1, vf[jn][1], z, 0, 0, 0);
    }
  }

  if (valid) {
#pragma unroll
    for (int i = 0; i < 4; ++i) {
#pragma unroll
      for (int r = 0; r < 4; ++r) {
        const float inv = 1.f / l[i][r];
        const size_t rowoff = qbase + (size_t)(16 * i + quad * 4 + r) * 512;
#pragma unroll
        for (int jn = 0; jn < 4; ++jn)
          qo[rowoff + 16 * jn + lm] = f2bf(oa[i][jn][r] * inv);
      }
    }
  }
}

// ---------------------------------------------------------------------------
// Workspace (bytes), preferred layout total 109,576,192 (unchanged):
//   qbuf  @ 0        : 50176*512*2  = 51,380,224  bf16 (q, then attn out)
//   kvbuf @ 51380224 : 1024*1024*4  =  4,194,304  fp32 (atomic split-K)
//   WkvT  @ 55574528 : 1024*12544*2 = 25,690,112  bf16
//   WqT   @ 81264640 : 512*256*2    =     262,144 bf16
//   WoT   @ 81526784 : 256*512*2    =     262,144 bf16
//   kvbf  @ 81788928 : 1024*1024*2  =  2,097,152  bf16
//   xpat  @ 83886080 : 12845056*2   = 25,690,112  bf16 patch-major im2col
// Fallback (< 110 MB): round-6 path (fp32 x with inline cvt), proven.
// ---------------------------------------------------------------------------
extern "C" void kernel_launch(void* const* d_in, const int* in_sizes, int n_in,
                              void* d_out, int out_size, void* d_ws,
                              size_t ws_size, hipStream_t stream) {
  const float* x = (const float*)d_in[0];
  const float* Wq = (const float*)d_in[1];
  const float* Wkv = (const float*)d_in[2];
  const float* Wo = (const float*)d_in[3];
  const float* bo = (const float*)d_in[4];
  float* out = (float*)d_out;

  char* ws = (char*)d_ws;
  ushort_t* qbuf = (ushort_t*)(ws);
  float* kvbuf = (float*)(ws + 51380224);
  ushort_t* WkvT = (ushort_t*)(ws + 55574528);
  ushort_t* WqT = (ushort_t*)(ws + 81264640);
  ushort_t* WoT = (ushort_t*)(ws + 81526784);
  ushort_t* kvbf = (ushort_t*)(ws + 81788928);
  ushort_t* xpat = (ushort_t*)(ws + 83886080);
  const bool use_fast = ws_size >= 109576192u;

  // 0) weight transposes + bf16 cvt; kvbuf zero for atomic split-K
  hipLaunchKernelGGL(transpose_cvt, dim3(16, 8), dim3(256), 0, stream, Wq, WqT,
                     256, 512);
  hipLaunchKernelGGL(transpose_cvt, dim3(32, 392), dim3(256), 0, stream, Wkv,
                     WkvT, 12544, 1024);
  hipLaunchKernelGGL(transpose_cvt, dim3(8, 16), dim3(256), 0, stream, Wo, WoT,
                     512, 256);
  hipMemsetAsync(kvbuf, 0, 1024 * 1024 * 4, stream);

  if (use_fast) {
    // 0b) x -> bf16 patch-major im2col pack (pure permutation, same bytes)
    hipLaunchKernelGGL(cvt_im2col, dim3(6272), dim3(256), 0, stream, x, xpat);
    // 1) Q projection (DEPTH=1, nst=8)
    hipLaunchKernelGGL((gemm_nt_2d<0, true>), dim3(4, 392), dim3(256), 0,
                       stream, xpat, WqT, (const float*)nullptr, qbuf, 512,
                       256);
    // 2) KV conv GEMM (DEPTH=2, nst=28), split-K=14
    hipLaunchKernelGGL(gemm_kv_gl, dim3(896), dim3(256), 0, stream, xpat,
                       WkvT, kvbuf);
    hipLaunchKernelGGL(cvt_f32_bf16, dim3(1024), dim3(256), 0, stream, kvbuf,
                       kvbf);
    // 3) MFMA attention, in-place on qbuf
    hipLaunchKernelGGL(attn_mfma, dim3(13, 128), dim3(256), 0, stream, qbuf,
                       kvbf);
    // 4) output projection + bias (DEPTH=1, nst=16)
    hipLaunchKernelGGL((gemm_nt_2d<1, false>), dim3(2, 392), dim3(256), 0,
                       stream, qbuf, WoT, bo, out, 256, 512);
  } else {
    hipLaunchKernelGGL((gemm_mfma_nt<float, ushort_t>), dim3(4, 392),
                       dim3(256), 0, stream, x, WqT, (const float*)nullptr,
                       qbuf, 50176, 512, 256, 0);
    hipLaunchKernelGGL((gemm_kv_mfma<float>), dim3(896), dim3(256), 0, stream,
                       x, WkvT, kvbuf);
    hipLaunchKernelGGL(cvt_f32_bf16, dim3(1024), dim3(256), 0, stream, kvbuf,
                       kvbf);
    hipLaunchKernelGGL(attn_mfma, dim3(13, 128), dim3(256), 0, stream, qbuf,
                       kvbf);
    hipLaunchKernelGGL((gemm_mfma_nt<ushort_t, float>), dim3(2, 392),
                       dim3(256), 0, stream, qbuf, WoT, bo, out, 50176, 256,
                       512, 1);
  }
}